// Round 7
// baseline (547.637 us; speedup 1.0000x reference)
//
#include <hip/hip_runtime.h>
#include <hip/hip_bf16.h>

#define B_   32
#define H_   128
#define W_   128
#define HW_  16384
#define C1_  128

typedef __attribute__((ext_vector_type(8))) short short8;
typedef __attribute__((ext_vector_type(4))) float f32x4;
typedef __attribute__((ext_vector_type(2))) float f32x2;

static __device__ __forceinline__ unsigned short bfbits(float f) {
    __hip_bfloat16 h = __float2bfloat16(f);
    return *reinterpret_cast<unsigned short*>(&h);
}
static __device__ __forceinline__ float bf2f(unsigned int u) {
    union { unsigned int ui; float f; } cv; cv.ui = u << 16; return cv.f;
}
static __device__ __forceinline__ unsigned short bftrunc(float f) {
    unsigned u = __builtin_bit_cast(unsigned, f);
    return (unsigned short)((u + 0x8000u) >> 16);
}
// pack two floats to bf16 pair (lo = a, hi = b), round-half-up
static __device__ __forceinline__ unsigned packbf2(float a, float b) {
    unsigned ua = __builtin_bit_cast(unsigned, a) + 0x8000u;
    unsigned ub = __builtin_bit_cast(unsigned, b) + 0x8000u;
    return __builtin_amdgcn_perm(ub, ua, 0x07060302u);
}

// ---- merged prep: w2t2, w1t, zero stats ----
__global__ __launch_bounds__(256) void prep_all(const float* __restrict__ w2,
                                                const float* __restrict__ w1,
                                                unsigned short* __restrict__ w2t2,
                                                unsigned short* __restrict__ w1t,
                                                float* __restrict__ st) {
    int idx = blockIdx.x * 256 + threadIdx.x;
    if (idx < 147456) {
        int e  = idx & 7;
        int co = (idx >> 3) & 127;
        int kg = (idx >> 10) & 3;
        int t  = idx >> 12;          // 0..35
        int kk = t % 9, cc = t / 9;
        int ci = cc * 32 + kg * 8 + e;
        w2t2[idx] = bfbits(w2[((size_t)co * 128 + ci) * 9 + kk]);
    } else if (idx < 151552) {
        int i2 = idx - 147456;
        int k = i2 & 31, ci = i2 >> 5;
        w1t[i2] = (k < 18) ? bfbits(w1[ci * 18 + k]) : (unsigned short)0;
    } else if (idx < 152064) {
        st[idx - 151552] = 0.f;
    }
}

// ---------------- gaussian splat: vertical pass (±16 window; tail < 3e-14) ----------------
__global__ __launch_bounds__(256) void gauss_v(const float* __restrict__ jmap,
                                               float* __restrict__ gtmp,
                                               const float* __restrict__ ga,
                                               const float* __restrict__ gb) {
    __shared__ float k1[255];
    float a = ga[0] / (gb[0] * gb[0]);
    for (int i = threadIdx.x; i < 255; i += 256) {
        float d = (float)(i - 127);
        k1[i] = expf(a * d * d);
    }
    __syncthreads();
    int b = blockIdx.y;
    int y = blockIdx.x * 2 + (threadIdx.x >> 7);
    int x = threadIdx.x & 127;
    const float* m = jmap + (size_t)b * HW_;
    int lo = y - 16; if (lo < 0) lo = 0;
    int hi = y + 16; if (hi > 127) hi = 127;
    float s = 0.f;
    for (int yy = lo; yy <= hi; ++yy) {
        float mv = m[yy * W_ + x];
        s += (mv == 1.0f) ? k1[yy - y + 127] : 0.f;
    }
    gtmp[(size_t)b * HW_ + y * W_ + x] = s;
}

// ---------------- gaussian splat: horizontal pass + finalize (in-place) ----------------
__global__ __launch_bounds__(256) void gauss_h(const float* __restrict__ jmap,
                                               float* __restrict__ gtmp,
                                               const float* __restrict__ ga,
                                               const float* __restrict__ gb) {
    __shared__ float k1[255];
    __shared__ float row[256];
    float a = ga[0] / (gb[0] * gb[0]);
    for (int i = threadIdx.x; i < 255; i += 256) {
        float d = (float)(i - 127);
        k1[i] = expf(a * d * d);
    }
    int b = blockIdx.y;
    int y0 = blockIdx.x * 2;
    int tid = threadIdx.x;
    row[tid] = gtmp[(size_t)b * HW_ + (y0 + (tid >> 7)) * W_ + (tid & 127)];
    __syncthreads();
    int y = y0 + (tid >> 7);
    int x = tid & 127;
    int base = (tid >> 7) * 128;
    int lo = x - 16; if (lo < 0) lo = 0;
    int hi = x + 16; if (hi > 127) hi = 127;
    float s = 0.f;
    for (int xx = lo; xx <= hi; ++xx)
        s += k1[xx - x + 127] * row[base + xx];
    float g = jmap[(size_t)b * HW_ + y * W_ + x] + s;
    g = (g <= 0.05f) ? 0.f : fminf(g, 1.0f);
    gtmp[(size_t)b * HW_ + y * W_ + x] = g;
}

// ---------------- conv1 stats only (exact f32) ----------------
__global__ __launch_bounds__(256) void conv1stats_k(const float* __restrict__ out5,
                                                    const float* __restrict__ w1,
                                                    const float* __restrict__ b1,
                                                    float* __restrict__ sum1,
                                                    float* __restrict__ sq1) {
    int cg = blockIdx.x;
    int b  = blockIdx.y;
    int tid = threadIdx.x;
    __shared__ float wsh[8][18];
    __shared__ float bsh[8];
    __shared__ float red[256];
    for (int i = tid; i < 144; i += 256) wsh[i / 18][i % 18] = w1[cg * 8 * 18 + i];
    if (tid < 8) bsh[tid] = b1[cg * 8 + tid];
    __syncthreads();
    float ls[8], lq[8];
    #pragma unroll
    for (int i = 0; i < 8; ++i) { ls[i] = 0.f; lq[i] = 0.f; }
    const float* in0 = out5 + (size_t)b * 5 * HW_;
    const float* in1 = in0 + HW_;
    for (int pos = tid; pos < HW_; pos += 256) {
        int y = pos >> 7, x = pos & 127;
        float v0[9], v1[9];
        #pragma unroll
        for (int ky = 0; ky < 3; ++ky)
            #pragma unroll
            for (int kx = 0; kx < 3; ++kx) {
                int yy = y + ky - 1, xx = x + kx - 1;
                bool ok = ((unsigned)yy < 128u) && ((unsigned)xx < 128u);
                v0[ky * 3 + kx] = ok ? in0[yy * W_ + xx] : 0.f;
                v1[ky * 3 + kx] = ok ? in1[yy * W_ + xx] : 0.f;
            }
        #pragma unroll
        for (int i = 0; i < 8; ++i) {
            float a = bsh[i];
            #pragma unroll
            for (int k = 0; k < 9; ++k) a += v0[k] * wsh[i][k] + v1[k] * wsh[i][9 + k];
            ls[i] += a; lq[i] += a * a;
        }
    }
    for (int i = 0; i < 8; ++i) {
        red[tid] = ls[i]; __syncthreads();
        for (int s = 128; s > 0; s >>= 1) { if (tid < s) red[tid] += red[tid + s]; __syncthreads(); }
        if (tid == 0) atomicAdd(&sum1[cg * 8 + i], red[0]);
        __syncthreads();
        red[tid] = lq[i]; __syncthreads();
        for (int s = 128; s > 0; s >>= 1) { if (tid < s) red[tid] += red[tid + s]; __syncthreads(); }
        if (tid == 0) atomicAdd(&sq1[cg * 8 + i], red[0]);
        __syncthreads();
    }
}

// ---------------- BN params ----------------
__global__ void bnp_k(const float* __restrict__ sum, const float* __restrict__ sq,
                      const float* __restrict__ gamma, const float* __restrict__ beta,
                      float* __restrict__ s, float* __restrict__ t) {
    int c = threadIdx.x;
    const float N = (float)(B_ * HW_);
    float m = sum[c] / N;
    float v = sq[c] / N - m * m;
    float sc = gamma[c] / sqrtf(v + 1e-5f);
    s[c] = sc;
    t[c] = beta[c] - sc * m;
}

// ---------------- conv2 via MFMA: 512-thr, co128 x pos256 (2 rows), 2048 blocks ----------
// 2 blocks/CU (77.7 KB LDS). Per cc: h1-from-raw phase, then 5 double-buffered
// 2-tap weight chunks staged via global_load_lds (1 barrier/chunk, DMA hidden).
#define INT_OFF 0          // inT: 4*130*40 = 20800 shorts
#define WC_OFF  20800      // 2 bufs x 8192 shorts
#define RAW_OFF 37184      // [2][6][132] = 1584 shorts
#define PRM_OFF 38768      // 512 floats (byte 77536)
__global__ __launch_bounds__(512, 4) void conv2_mfma(
    const float* __restrict__ out5,
    const float* __restrict__ b1,
    const float* __restrict__ s1,
    const float* __restrict__ t1,
    const unsigned short* __restrict__ w2t2,
    const unsigned short* __restrict__ w1t,
    const float* __restrict__ b2,
    __hip_bfloat16* __restrict__ y2,
    float* __restrict__ sum2,
    float* __restrict__ sq2)
{
    __shared__ __align__(16) unsigned short lds[39792];
    float* prm  = (float*)&lds[PRM_OFF];
    float* s1sh = prm;        float* t1sh = prm + 128;
    float* redS = prm + 256;  float* redQ = prm + 384;

    const int tid = threadIdx.x;
    const int b  = blockIdx.x >> 6;
    const int y0 = (blockIdx.x & 63) * 2;
    const int lane = tid & 63, w = tid >> 6;       // 8 waves
    const int wm = w & 1, wn = w >> 1;             // co half / pos-64 group
    const int l15 = lane & 15, kg = lane >> 4;

    if (tid < 128) {
        redS[tid] = 0.f; redQ[tid] = 0.f;
        float sv = s1[tid]; s1sh[tid] = sv;
        t1sh[tid] = fmaf(sv, b1[tid], t1[tid]);    // fold conv1 bias into BN shift
    }

    // ---- stage raw input tile as bf16 [ch][6 rows][132 cols], pads zeroed ----
    const float* in0 = out5 + (size_t)b * 5 * HW_;
    const float* in1 = in0 + HW_;
    for (int t = tid; t < 1584; t += 512) {
        int ch = t / 792; int rm = t - ch * 792;
        int row = rm / 132; int scol = rm - row * 132;
        int gy = y0 - 2 + row, gx = scol - 2;
        float v = 0.f;
        if ((unsigned)gy < 128u && (unsigned)gx < 128u)
            v = (ch ? in1 : in0)[gy * W_ + gx];
        lds[RAW_OFF + t] = bftrunc(v);
    }

    // issue DMA for cc0 chunk0 (taps 0,1) into buf0
    {
        const unsigned short* src = w2t2;
        #pragma unroll
        for (int u = 0; u < 2; ++u)
            __builtin_amdgcn_global_load_lds(
                (const unsigned int*)(src + u * 4096 + tid * 8),
                (unsigned int*)&lds[WC_OFF + u * 4096 + tid * 8], 16, 0, 0);
    }

    // per-thread raw offsets for the 8 h1-frag elements (k = kg*8+j)
    int offj[8]; int valj[8];
    #pragma unroll
    for (int j = 0; j < 8; ++j) {
        int kidx = kg * 8 + j;
        int ch = (kidx >= 9) ? 1 : 0;
        int km = kidx - ch * 9;
        int ky = km / 3, kx = km - (km / 3) * 3;
        offj[j] = ch * 792 + ky * 132 + kx;
        valj[j] = (kidx < 18) ? 1 : 0;
    }

    __syncthreads();   // raw + prm ready (DMA also drained, harmless)

    f32x4 acc[4][4];
    #pragma unroll
    for (int fm = 0; fm < 4; ++fm)
        #pragma unroll
        for (int fn = 0; fn < 4; ++fn) acc[fm][fn] = (f32x4){0.f, 0.f, 0.f, 0.f};

    int parity = 0;
    for (int cc = 0; cc < 4; ++cc) {
        // ---- h1 phase: conv1+BN1+ReLU via MFMA from raw LDS -> inT ----
        short8 a1c0 = *(const short8*)&w1t[(cc * 32 + l15) * 32 + kg * 8];
        short8 a1c1 = *(const short8*)&w1t[(cc * 32 + 16 + l15) * 32 + kg * 8];
        for (int t = w; t < 66; t += 8) {
            int mi = t & 1, nj = t >> 1;
            int q = nj * 16 + l15;
            bool ok = q < 520;
            int r = q / 130, c = q - r * 130;
            int qb = ok ? (r * 132 + c) : 0;
            short8 bfb = (short8){0,0,0,0,0,0,0,0};
            #pragma unroll
            for (int j = 0; j < 8; ++j) {
                if (valj[j]) {
                    unsigned short v = lds[RAW_OFF + qb + offj[j]];
                    bfb[j] = ok ? (short)v : (short)0;
                }
            }
            f32x4 hacc = (f32x4){0.f, 0.f, 0.f, 0.f};
            hacc = __builtin_amdgcn_mfma_f32_16x16x32_bf16(mi ? a1c1 : a1c0, bfb, hacc, 0, 0, 0);
            if (ok) {
                int gy = y0 - 1 + r;
                bool zero = ((unsigned)gy >= 128u) || (c == 0) || (c == 129);
                int cigb = cc * 32 + mi * 16 + kg * 4;
                float h0 = fmaxf(fmaf(s1sh[cigb],     hacc[0], t1sh[cigb]),     0.f);
                float h1 = fmaxf(fmaf(s1sh[cigb + 1], hacc[1], t1sh[cigb + 1]), 0.f);
                float h2 = fmaxf(fmaf(s1sh[cigb + 2], hacc[2], t1sh[cigb + 2]), 0.f);
                float h3 = fmaxf(fmaf(s1sh[cigb + 3], hacc[3], t1sh[cigb + 3]), 0.f);
                unsigned long long pk = zero ? 0ull
                    : ((unsigned long long)packbf2(h2, h3) << 32) | packbf2(h0, h1);
                *(unsigned long long*)&lds[INT_OFF + (r * 130 + c) * 40 + mi * 16 + kg * 4] = pk;
            }
        }
        __syncthreads();   // inT ready; chunk[parity] DMA drained

        #pragma unroll
        for (int ch_ = 0; ch_ < 5; ++ch_) {
            // issue next chunk's DMA into the other buffer (hidden under this MFMA)
            if (ch_ < 4) {
                const int tap0 = (ch_ + 1) * 2;
                const int ntap = (ch_ == 3) ? 1 : 2;
                const unsigned short* src = w2t2 + cc * 36864 + tap0 * 4096;
                unsigned short* dst = &lds[WC_OFF + (parity ^ 1) * 8192];
                for (int u = 0; u < ntap; ++u)
                    __builtin_amdgcn_global_load_lds(
                        (const unsigned int*)(src + u * 4096 + tid * 8),
                        (unsigned int*)(dst + u * 4096 + tid * 8), 16, 0, 0);
            } else if (cc < 3) {
                const unsigned short* src = w2t2 + (cc + 1) * 36864;
                unsigned short* dst = &lds[WC_OFF + (parity ^ 1) * 8192];
                #pragma unroll
                for (int u = 0; u < 2; ++u)
                    __builtin_amdgcn_global_load_lds(
                        (const unsigned int*)(src + u * 4096 + tid * 8),
                        (unsigned int*)(dst + u * 4096 + tid * 8), 16, 0, 0);
            }
            // MFMA this chunk
            const unsigned short* buf = &lds[WC_OFF + parity * 8192];
            const int ntap_c = (ch_ == 4) ? 1 : 2;
            #pragma unroll
            for (int t2 = 0; t2 < 2; ++t2) {
                if (t2 >= ntap_c) break;
                const int kk = ch_ * 2 + t2;
                const int ky = kk / 3, kx = kk - (kk / 3) * 3;
                short8 af[4], bv[4];
                #pragma unroll
                for (int fm = 0; fm < 4; ++fm)
                    af[fm] = *(const short8*)&buf[((t2 * 4 + kg) * 128 + wm * 64 + fm * 16 + l15) * 8];
                #pragma unroll
                for (int fn = 0; fn < 4; ++fn) {
                    int n = wn * 64 + fn * 16 + l15;
                    int r2 = (n >> 7) + ky, c2 = (n & 127) + kx;
                    bv[fn] = *(const short8*)&lds[INT_OFF + (r2 * 130 + c2) * 40 + kg * 8];
                }
                #pragma unroll
                for (int fm = 0; fm < 4; ++fm)
                    #pragma unroll
                    for (int fn = 0; fn < 4; ++fn)
                        acc[fm][fn] = __builtin_amdgcn_mfma_f32_16x16x32_bf16(af[fm], bv[fn], acc[fm][fn], 0, 0, 0);
            }
            __syncthreads();   // buf reads done; next chunk's DMA drained
            parity ^= 1;
        }
    }

    // ---- epilogue: stats + coalesced y2 via LDS repack (pt = inT region) ----
    unsigned short* pt = lds;
    #pragma unroll
    for (int fm = 0; fm < 4; ++fm)
        #pragma unroll
        for (int r = 0; r < 4; ++r) {
            int co = wm * 64 + fm * 16 + kg * 4 + r;
            float bb = b2[co];
            float ls = 0.f, lq = 0.f;
            #pragma unroll
            for (int fn = 0; fn < 4; ++fn) { float v = acc[fm][fn][r] + bb; ls += v; lq += v * v; }
            #pragma unroll
            for (int m = 1; m < 16; m <<= 1) {
                ls += __shfl_xor(ls, m, 64);
                lq += __shfl_xor(lq, m, 64);
            }
            if (l15 == 0) { atomicAdd(&redS[co], ls); atomicAdd(&redQ[co], lq); }
        }
    if (wm == 0) {
        #pragma unroll
        for (int fm = 0; fm < 4; ++fm)
            #pragma unroll
            for (int r = 0; r < 4; ++r) {
                int col = fm * 16 + kg * 4 + r;
                float bb = b2[col];
                int xr = ((col >> 2) & 3) << 4;
                #pragma unroll
                for (int fn = 0; fn < 4; ++fn) {
                    int n = wn * 64 + fn * 16 + l15;
                    pt[col * 256 + (n ^ xr)] = bftrunc(acc[fm][fn][r] + bb);
                }
            }
    }
    __syncthreads();
    if (tid < 128) { atomicAdd(&sum2[tid], redS[tid]); atomicAdd(&sq2[tid], redQ[tid]); }
    {
        unsigned short* y2u = (unsigned short*)y2;
        int co_l = tid >> 3, sub = tid & 7;
        int xr = ((co_l >> 2) & 3) << 4;
        #pragma unroll
        for (int j = 0; j < 4; ++j) {
            int p = j * 64 + sub * 8;
            size_t idx = (((size_t)b * C1_ + co_l) * H_ + y0 + (p >> 7)) * (size_t)W_ + (p & 127);
            *(short8*)&y2u[idx] = *(short8*)&pt[co_l * 256 + (p ^ xr)];
        }
    }
    __syncthreads();
    if (wm == 1) {
        #pragma unroll
        for (int fm = 0; fm < 4; ++fm)
            #pragma unroll
            for (int r = 0; r < 4; ++r) {
                int col = fm * 16 + kg * 4 + r;
                float bb = b2[64 + col];
                int xr = ((col >> 2) & 3) << 4;
                #pragma unroll
                for (int fn = 0; fn < 4; ++fn) {
                    int n = wn * 64 + fn * 16 + l15;
                    pt[col * 256 + (n ^ xr)] = bftrunc(acc[fm][fn][r] + bb);
                }
            }
    }
    __syncthreads();
    {
        unsigned short* y2u = (unsigned short*)y2;
        int co_l = tid >> 3, sub = tid & 7;
        int xr = ((co_l >> 2) & 3) << 4;
        #pragma unroll
        for (int j = 0; j < 4; ++j) {
            int p = j * 64 + sub * 8;
            size_t idx = (((size_t)b * C1_ + 64 + co_l) * H_ + y0 + (p >> 7)) * (size_t)W_ + (p & 127);
            *(short8*)&y2u[idx] = *(short8*)&pt[co_l * 256 + (p ^ xr)];
        }
    }
}

// ---------------- lateral path: maxpool2 + conv3x3(2->2) pad1 ----------------
__global__ __launch_bounds__(256) void poolconv_k(const float* __restrict__ out5,
                                                  const float* __restrict__ wl,
                                                  const float* __restrict__ bl,
                                                  float* __restrict__ ds) {
    int idx = blockIdx.x * 256 + threadIdx.x;
    int j = idx & 63;
    int i = (idx >> 6) & 63;
    int c = (idx >> 12) & 1;
    int b = idx >> 13;
    float acc = bl[c];
    #pragma unroll
    for (int ci = 0; ci < 2; ++ci) {
        const float* in = out5 + ((size_t)b * 5 + ci) * HW_;
        #pragma unroll
        for (int ky = 0; ky < 3; ++ky) {
            int ii = i + ky - 1;
            if (ii < 0 || ii > 63) continue;
            #pragma unroll
            for (int kx = 0; kx < 3; ++kx) {
                int jj = j + kx - 1;
                if (jj < 0 || jj > 63) continue;
                const float* p = in + (2 * ii) * W_ + 2 * jj;
                float pooled = fmaxf(fmaxf(p[0], p[1]), fmaxf(p[W_], p[W_ + 1]));
                acc += pooled * wl[(c * 2 + ci) * 9 + ky * 3 + kx];
            }
        }
    }
    ds[idx] = acc;
}

// ---------------- final: conv1x1(BN2+ReLU) + upsample + softmax + sigmoids, 2 px/thr ----
__global__ __launch_bounds__(256) void final_k(const float* __restrict__ out5,
                                               const __hip_bfloat16* __restrict__ y2,
                                               const float* __restrict__ s2,
                                               const float* __restrict__ t2,
                                               const float* __restrict__ w3,
                                               const float* __restrict__ b3,
                                               const float* __restrict__ dsb,
                                               float* __restrict__ out) {
    __shared__ float w3s[256], s2s[128], t2s[128];
    int tid = threadIdx.x;
    w3s[tid] = w3[tid];
    if (tid < 128) { s2s[tid] = s2[tid]; t2s[tid] = t2[tid]; }
    __syncthreads();
    int gid = blockIdx.x * 256 + tid;       // 262144 = 32*128*64
    int b = gid >> 13;
    int rem = gid & 8191;
    int y = rem >> 6;
    int x0 = (rem & 63) * 2;
    int p = y * W_ + x0;

    const unsigned short* yp = (const unsigned short*)y2 + (size_t)b * C1_ * HW_ + p;
    float jm0a = b3[0], jm1a = b3[1], jm0b = b3[0], jm1b = b3[1];
    for (int ci = 0; ci < 128; ++ci) {
        unsigned int v = *(const unsigned int*)(yp + (size_t)ci * HW_);
        float sc = s2s[ci], tc = t2s[ci];
        float w0 = w3s[ci], w1c = w3s[128 + ci];
        float h0 = fmaxf(fmaf(sc, bf2f(v & 0xffffu), tc), 0.f);
        float h1 = fmaxf(fmaf(sc, bf2f(v >> 16), tc), 0.f);
        jm0a = fmaf(h0, w0, jm0a); jm1a = fmaf(h0, w1c, jm1a);
        jm0b = fmaf(h1, w0, jm0b); jm1b = fmaf(h1, w1c, jm1b);
    }

    const float fo = (float)(63.0 / 127.0);
    float sy = (float)y * fo;
    int ly = (int)floorf(sy); ly = ly < 0 ? 0 : (ly > 62 ? 62 : ly);
    float wy = sy - (float)ly;
    const float* dbase = dsb + ((size_t)b * 2) * 4096;
    float sig[2];
    float jm0[2] = {jm0a, jm0b}, jm1[2] = {jm1a, jm1b};
    #pragma unroll
    for (int i = 0; i < 2; ++i) {
        int x = x0 + i;
        float sx = (float)x * fo;
        int lx = (int)floorf(sx); lx = lx < 0 ? 0 : (lx > 62 ? 62 : lx);
        float wx = sx - (float)lx;
        float up[2];
        #pragma unroll
        for (int c = 0; c < 2; ++c) {
            const float* d = dbase + c * 4096;
            float d00 = d[ly * 64 + lx],       d01 = d[ly * 64 + lx + 1];
            float d10 = d[(ly + 1) * 64 + lx], d11 = d[(ly + 1) * 64 + lx + 1];
            up[c] = (1.f - wy) * ((1.f - wx) * d00 + wx * d01) + wy * ((1.f - wx) * d10 + wx * d11);
        }
        float dlt = (jm1[i] + up[1]) - (jm0[i] + up[0]);
        sig[i] = 1.f / (1.f + expf(-dlt));
    }
    *(f32x2*)&out[(size_t)b * HW_ + p] = (f32x2){sig[0], sig[1]};

    float lm0 = out5[((size_t)b * 5 + 2) * HW_ + p];
    float lm1 = out5[((size_t)b * 5 + 2) * HW_ + p + 1];
    *(f32x2*)&out[524288 + (size_t)b * HW_ + p] =
        (f32x2){1.f / (1.f + expf(-lm0)), 1.f / (1.f + expf(-lm1))};

    float o30 = out5[((size_t)b * 5 + 3) * HW_ + p];
    float o31 = out5[((size_t)b * 5 + 3) * HW_ + p + 1];
    float o40 = out5[((size_t)b * 5 + 4) * HW_ + p];
    float o41 = out5[((size_t)b * 5 + 4) * HW_ + p + 1];
    *(f32x2*)&out[1048576 + ((size_t)b * 2 + 0) * HW_ + p] =
        (f32x2){1.f / (1.f + expf(-o30)) - 0.5f, 1.f / (1.f + expf(-o31)) - 0.5f};
    *(f32x2*)&out[1048576 + ((size_t)b * 2 + 1) * HW_ + p] =
        (f32x2){1.f / (1.f + expf(-o40)) - 0.5f, 1.f / (1.f + expf(-o41)) - 0.5f};
}

extern "C" void kernel_launch(void* const* d_in, const int* in_sizes, int n_in,
                              void* d_out, int out_size, void* d_ws, size_t ws_size,
                              hipStream_t stream) {
    const float* out5 = (const float*)d_in[0];
    const float* jmap = (const float*)d_in[1];
    const float* w1   = (const float*)d_in[2];
    const float* b1   = (const float*)d_in[3];
    const float* g1   = (const float*)d_in[4];
    const float* be1  = (const float*)d_in[5];
    const float* w2   = (const float*)d_in[6];
    const float* b2   = (const float*)d_in[7];
    const float* g2   = (const float*)d_in[8];
    const float* be2  = (const float*)d_in[9];
    const float* w3   = (const float*)d_in[10];
    const float* b3   = (const float*)d_in[11];
    const float* wl   = (const float*)d_in[12];
    const float* bl   = (const float*)d_in[13];
    const float* ga   = (const float*)d_in[14];
    const float* gb   = (const float*)d_in[15];
    float* out = (float*)d_out;

    // ws layout (~135.3 MB):
    //   [0, 134217728)           y2 bf16
    //   [134217728, +294912)     w2t2 } overlapped later by dsb (disjoint lifetimes)
    //   [134512640, +8192)       w1t  }
    //   [134217728, +1048576)    dsb (poolconv out; written after conv2 done)
    //   [135266304, +4096)       stats
    char* ws = (char*)d_ws;
    __hip_bfloat16* y2 = (__hip_bfloat16*)ws;
    unsigned short* w2t2 = (unsigned short*)(ws + 134217728);
    unsigned short* w1t  = (unsigned short*)(ws + 134512640);
    float* dsb = (float*)(ws + 134217728);
    float* st  = (float*)(ws + 135266304);
    float* sum1 = st;        float* sq1 = st + 128;
    float* sum2 = st + 256;  float* sq2 = st + 384;
    float* s1 = st + 512;    float* t1 = st + 640;
    float* s2 = st + 768;    float* t2 = st + 896;

    float* gtmp = out + 2097152;   // gauss region doubles as vertical-pass temp

    prep_all<<<594, 256, 0, stream>>>(w2, w1, w2t2, w1t, st);
    gauss_v<<<dim3(64, 32), 256, 0, stream>>>(jmap, gtmp, ga, gb);
    gauss_h<<<dim3(64, 32), 256, 0, stream>>>(jmap, gtmp, ga, gb);
    conv1stats_k<<<dim3(16, 32), 256, 0, stream>>>(out5, w1, b1, sum1, sq1);
    bnp_k<<<1, 128, 0, stream>>>(sum1, sq1, g1, be1, s1, t1);
    conv2_mfma<<<2048, 512, 0, stream>>>(out5, b1, s1, t1, w2t2, w1t, b2, y2, sum2, sq2);
    bnp_k<<<1, 128, 0, stream>>>(sum2, sq2, g2, be2, s2, t2);
    poolconv_k<<<1024, 256, 0, stream>>>(out5, wl, bl, dsb);
    final_k<<<1024, 256, 0, stream>>>(out5, y2, s2, t2, w3, b3, dsb, out);
}